// Round 12
// baseline (298.012 us; speedup 1.0000x reference)
//
#include <hip/hip_runtime.h>

// B=16, L=2048, V=64.
// Algebraic reduction (e is one-hot):
//   E[d] = exp(v_emb[d]); S[t] = prefix_sum(E)[t]
//   F[b,c,s] = sum_{k<=s} E[s-k] * Wq[idx[b,k], c]            (causal Toeplitz GEMM)
//   P[b,c,s] = exp(F[b,c,s] / S[s])                           (softmax w/o max; scores tiny)
//   out[b,t,v] = Wv00 * (sum_{s<=t, idx[b,s]==v} P[b,c_t,s]) / (sum_{s<=t} P[b,c_t,s]),  c_t = idx[b,t]
//
// R12: gemm restructured for occupancy: 2048 blocks (16-wide n-tiles), wave =
// M32xN16 (2 MFMA/iter), 2 M-halves x 2 k-halves per block, launch_bounds
// (256,8) -> 8 waves/SIMD (2x latency cover). GL0/GL1 parity select hoisted
// (K-step 64 => invariant). K-extent rounded to x32 via GLv zero-padding.
// gather + scanemit unchanged (R11-verified).

#define LSEQ 2048
#define NB 16
#define NV 64
#define NC 32             // 32 chunks of 64

typedef __attribute__((ext_vector_type(8))) short bf16x8;
typedef __attribute__((ext_vector_type(4))) float f32x4;

__device__ __forceinline__ unsigned short f2bf(float f) {   // RNE float->bf16
  unsigned int u = __float_as_uint(f);
  return (unsigned short)((u + 0x7FFFu + ((u >> 16) & 1u)) >> 16);
}

// ---------------- K0: gather + (fused) prep ------------------------------------
// Agr[((b*256 + k8)*64 + c)*8 + j] = bf16(Wq[idx[b, 2047-(k8*8+j)]][c])
__global__ __launch_bounds__(256) void k_gather(const int* __restrict__ idx,
                                                const float* __restrict__ Wq,
                                                const float* __restrict__ v_emb,
                                                unsigned short* __restrict__ Agr,
                                                unsigned short* __restrict__ Ebf,
                                                float* __restrict__ S) {
  const int b = blockIdx.x >> 4;
  const int tile = blockIdx.x & 15;
  const int w = threadIdx.x >> 6;
  const int lane = threadIdx.x & 63;

  if (blockIdx.x == 0 && threadIdx.x < 64) {   // fused prep (one wave)
    const int base = lane * 32;
    float e[32];
    float run = 0.f;
#pragma unroll
    for (int i = 0; i < 32; ++i) { e[i] = expf(v_emb[base + i]); run += e[i]; }
    float incl = run;
#pragma unroll
    for (int d = 1; d < 64; d <<= 1) {
      float up = __shfl_up(incl, d);
      if (lane >= d) incl += up;
    }
    float acc = incl - run;
#pragma unroll
    for (int i = 0; i < 32; ++i) {
      acc += e[i];
      Ebf[base + i] = f2bf(e[i]);
      S[base + i] = acc;
    }
  }

  const int k8base = tile * 16 + w * 4;        // this wave's 4 k8-groups
#pragma unroll
  for (int r = 0; r < 4; ++r) {
    const int k8 = k8base + r;
    unsigned short v[8];
#pragma unroll
    for (int j = 0; j < 8; ++j) {
      const int ii = idx[b * LSEQ + (2047 - (k8 * 8 + j))];  // wave-uniform
      v[j] = f2bf(Wq[ii * 64 + lane]);                       // coalesced row read
    }
    uint4 st;
    st.x = (unsigned int)v[0] | ((unsigned int)v[1] << 16);
    st.y = (unsigned int)v[2] | ((unsigned int)v[3] << 16);
    st.z = (unsigned int)v[4] | ((unsigned int)v[5] << 16);
    st.w = (unsigned int)v[6] | ((unsigned int)v[7] << 16);
    *(uint4*)(Agr + ((size_t)(b * 256 + k8) * 64 + lane) * 8) = st;  // 16B/lane coalesced
  }
}

// ---------------- K1: MFMA GEMM -> P[(b*64+c)][s] = exp(F/S[s]) ----------------
// Block = (b, 16-wide n-tile); 4 waves = 2 M-halves x 2 k-halves.
// Wave: M32 x N16, 2 MFMA per 32-k iter, ping-pong prefetch.
// GLv(i) = (127<=i<2175) ? E[i-127] : 0; staged window [96, n0+144).
__global__ __launch_bounds__(256, 8) void k_gemm(const unsigned short* __restrict__ Agr,
                                                 const unsigned short* __restrict__ Ebf,
                                                 const float* __restrict__ S,
                                                 float* __restrict__ P) {
  __shared__ unsigned short GL0[2208];   // GL0[i] = GLv(i)
  __shared__ unsigned short GL1[2176];   // GL1[i] = GLv(i+1)
  __shared__ float red[2][8][64];        // kh=1 partials per M-half

  const int b  = blockIdx.y;
  const int bn = 127 - (int)blockIdx.x;      // heavy (long-K) blocks first
  const int n0 = bn * 16;
  const int tid = threadIdx.x;
  const int w = tid >> 6;
  const int lane = tid & 63;
  const int quad = lane >> 4;
  const int lm = lane & 15;
  const int msub = w & 1;                    // M-half: c-offset 0 / 32
  const int kh = w >> 1;                     // k-half 0 / 1

  // stage the window this tile reads: i in [96, n0+144)
  {
    const int wend = n0 + 144;
    for (int i = 96 + tid; i < wend; i += 256) {
      const int e0 = i - 127;
      const int e1 = i - 126;
      GL0[i] = (e0 >= 0 && e0 < LSEQ) ? Ebf[e0] : (unsigned short)0;
      GL1[i] = (e1 >= 0 && e1 < LSEQ) ? Ebf[e1] : (unsigned short)0;
    }
  }
  __syncthreads();

  f32x4 acc[2];
  acc[0] = (f32x4){0.f, 0.f, 0.f, 0.f};
  acc[1] = (f32x4){0.f, 0.f, 0.f, 0.f};

  const int sbase = n0 + lm - 1920;
  const int kext = (n0 + 16 + 31) & ~31;     // K-extent rounded up to x32
  const int kstart = 2048 - kext;            // extra low-k entries hit GLv()=0
  const int iters = kext >> 5;               // total 32-k steps
  const unsigned short* __restrict__ abase = Agr + (size_t)b * 256 * 64 * 8;
  // parity of s_ is invariant across iters (k-step 64, quad*8 even)
  const unsigned int* __restrict__ gb =
      (sbase & 1) ? (const unsigned int*)GL1 : (const unsigned int*)GL0;

  union AF { uint4 u; bf16x8 v; };
  union BF { unsigned int u[4]; bf16x8 v; };
  AF a[2][2];
  BF bb[2];

#define LOAD_FRAGS(J_, SL) do {                                             \
    const int k_ = kstart + (kh + 2 * (J_)) * 32;                           \
    const int kq8_ = (k_ >> 3) + quad;                                      \
    const unsigned short* ab_ = abase + ((size_t)kq8_ * 64 + msub * 32 + lm) * 8; \
    a[SL][0].u = *(const uint4*)(ab_ + 0 * 128);                            \
    a[SL][1].u = *(const uint4*)(ab_ + 1 * 128);                            \
    const int off_ = (sbase + k_ + quad * 8) >> 1;                          \
    bb[SL].u[0] = gb[off_ + 0]; bb[SL].u[1] = gb[off_ + 1];                 \
    bb[SL].u[2] = gb[off_ + 2]; bb[SL].u[3] = gb[off_ + 3];                 \
  } while (0)

#define MFMA2(SL) do {                                                      \
    acc[0] = __builtin_amdgcn_mfma_f32_16x16x32_bf16(a[SL][0].v, bb[SL].v, acc[0], 0, 0, 0); \
    acc[1] = __builtin_amdgcn_mfma_f32_16x16x32_bf16(a[SL][1].v, bb[SL].v, acc[1], 0, 0, 0); \
  } while (0)

  const int J = (iters > kh) ? ((iters - kh + 1) >> 1) : 0;  // wave-iters
  if (J > 0) {
    LOAD_FRAGS(0, 0);
    int j = 0;
    while (true) {
      if (j + 1 < J) LOAD_FRAGS(j + 1, (j + 1) & 1);
      MFMA2(j & 1);
      if (++j >= J) break;
    }
  }
#undef LOAD_FRAGS
#undef MFMA2

  // reduce k-half 1 into k-half 0 via LDS (lane-contiguous rows: conflict-free)
  if (kh == 1) {
#pragma unroll
    for (int mt = 0; mt < 2; ++mt)
#pragma unroll
      for (int r = 0; r < 4; ++r) red[msub][mt * 4 + r][lane] = acc[mt][r];
  }
  __syncthreads();
  if (kh == 0) {
#pragma unroll
    for (int mt = 0; mt < 2; ++mt)
#pragma unroll
      for (int r = 0; r < 4; ++r) acc[mt][r] += red[msub][mt * 4 + r][lane];

    // epilogue: C/D layout col(s)=lm, row(c)=quad*4+r
    const float sinv = 1.0f / S[n0 + lm];
#pragma unroll
    for (int mt = 0; mt < 2; ++mt) {
#pragma unroll
      for (int r = 0; r < 4; ++r) {
        const int c = msub * 32 + mt * 16 + quad * 4 + r;
        P[((size_t)(b * 64 + c)) * LSEQ + n0 + lm] = __expf(acc[mt][r] * sinv);
      }
    }
  }
}

// ---------------- K2: fused chunk-hists + scan + emission ----------------------
// Block per (b,c); wave w owns chunks w*8..w*8+7 (held in registers).
// (1) scatter chunk hists into Hs (stride-65 rows), (2) shfl exclusive scan
// across chunks per bin, (3) ballot-enumerate emission points t (idx[b,t]==c),
// (4) per t: masked single ds_add scatter + prefix + z-reduce + 256B store.
__global__ __launch_bounds__(256) void k_scanemit(const int* __restrict__ idx,
                                                  const float* __restrict__ P,
                                                  const float* __restrict__ Wv,
                                                  float* __restrict__ out) {
  __shared__ float Hs[NC][65];
  __shared__ float bins[4][64];
  const int bc = blockIdx.x;      // b*64 + c
  const int b = bc >> 6;
  const int c = bc & 63;
  const int w = threadIdx.x >> 6;
  const int lane = threadIdx.x & 63;

  const float* __restrict__ prow = P + (size_t)bc * LSEQ;
  const int* __restrict__ irow = idx + b * LSEQ;

  float p[8]; int ii[8];
#pragma unroll
  for (int r = 0; r < 8; ++r) {               // 16 independent coalesced loads
    const int ch = w * 8 + r;
    p[r] = prow[ch * 64 + lane];
    ii[r] = irow[ch * 64 + lane];
  }
  for (int i = threadIdx.x; i < NC * 65; i += 256) ((float*)Hs)[i] = 0.f;
  __syncthreads();
#pragma unroll
  for (int r = 0; r < 8; ++r) atomicAdd(&Hs[w * 8 + r][ii[r]], p[r]);
  __syncthreads();

  // exclusive scan across chunks, per bin: 2 bins per pass (lane halves)
  const int half = lane >> 5, l32 = lane & 31;
#pragma unroll
  for (int r = 0; r < 8; ++r) {
    const int v = w * 16 + r * 2 + half;
    const float h = Hs[l32][v];
    float x = h;
#pragma unroll
    for (int d = 1; d < 32; d <<= 1) {
      float up = __shfl_up(x, d, 32);
      if (l32 >= d) x += up;
    }
    Hs[l32][v] = x - h;                       // exclusive
  }
  __syncthreads();

  const float wv = Wv[0];
#pragma unroll
  for (int r = 0; r < 8; ++r) {
    const int ch = w * 8 + r;
    unsigned long long m = __ballot(ii[r] == c);   // emission points in chunk
    while (m) {
      const int srel = __builtin_ctzll(m);
      m &= m - 1;
      const int t = ch * 64 + srel;
      const float pm = (lane <= srel) ? p[r] : 0.f;  // causal mask
      bins[w][lane] = 0.f;
      __threadfence_block();
      atomicAdd(&bins[w][ii[r]], pm);              // one ds_add per emission
      __threadfence_block();
      const float bin = bins[w][lane] + Hs[ch][lane];
      float z = bin;
#pragma unroll
      for (int d = 1; d < 64; d <<= 1) z += __shfl_xor(z, d);
      out[((size_t)(b * LSEQ + t)) * 64 + lane] = wv * bin / z;
    }
  }
}

extern "C" void kernel_launch(void* const* d_in, const int* in_sizes, int n_in,
                              void* d_out, int out_size, void* d_ws, size_t ws_size,
                              hipStream_t stream) {
  const int* idx     = (const int*)d_in[0];     // [16, 2048]
  const float* Wq    = (const float*)d_in[1];   // [64, 64]
  const float* Wv    = (const float*)d_in[2];   // [64, 64] (only [0,0] used)
  const float* v_emb = (const float*)d_in[3];   // [2048, 1]
  float* out = (float*)d_out;                   // [16, 2048, 64] fp32

  // workspace: S[2048] f32 | P[1024*2048] f32 | Ebf[2048] bf16 | Agr[16*256*64*8] bf16
  float* S = (float*)d_ws;
  float* P = S + LSEQ;
  unsigned short* Ebf = (unsigned short*)(P + (size_t)NB * NV * LSEQ);
  unsigned short* Agr = Ebf + LSEQ;

  k_gather<<<NB * 16, 256, 0, stream>>>(idx, Wq, v_emb, Agr, Ebf, S);
  k_gemm<<<dim3(128, NB), 256, 0, stream>>>(Agr, Ebf, S, P);
  k_scanemit<<<NB * NV, 256, 0, stream>>>(idx, P, Wv, out);
}

// Round 13
// 121.732 us; speedup vs baseline: 2.4481x; 2.4481x over previous
//
#include <hip/hip_runtime.h>

// B=16, L=2048, V=64.
// Algebraic reduction (e is one-hot):
//   E[d] = exp(v_emb[d]); S[t] = prefix_sum(E)[t]
//   F[b,c,s] = sum_{k<=s} E[s-k] * Wq[idx[b,k], c]            (causal Toeplitz GEMM)
//   P[b,c,s] = exp(F[b,c,s] / S[s])                           (softmax w/o max; scores tiny)
//   out[b,t,v] = Wv00 * (sum_{s<=t, idx[b,s]==v} P[b,c_t,s]) / (sum_{s<=t} P[b,c_t,s]),  c_t = idx[b,t]
//
// R13: R12's occupancy plan (2048 blocks, M32xN16 waves, 8 waves/SIMD) with the
// scratch-spill bug fixed: pipeline slots are LITERAL indices again (runtime
// array indices demoted a[]/bb[] to scratch -> 250MB spill traffic, 200us).
// gather + scanemit unchanged (R11-verified).

#define LSEQ 2048
#define NB 16
#define NV 64
#define NC 32             // 32 chunks of 64

typedef __attribute__((ext_vector_type(8))) short bf16x8;
typedef __attribute__((ext_vector_type(4))) float f32x4;

__device__ __forceinline__ unsigned short f2bf(float f) {   // RNE float->bf16
  unsigned int u = __float_as_uint(f);
  return (unsigned short)((u + 0x7FFFu + ((u >> 16) & 1u)) >> 16);
}

// ---------------- K0: gather + (fused) prep ------------------------------------
// Agr[((b*256 + k8)*64 + c)*8 + j] = bf16(Wq[idx[b, 2047-(k8*8+j)]][c])
__global__ __launch_bounds__(256) void k_gather(const int* __restrict__ idx,
                                                const float* __restrict__ Wq,
                                                const float* __restrict__ v_emb,
                                                unsigned short* __restrict__ Agr,
                                                unsigned short* __restrict__ Ebf,
                                                float* __restrict__ S) {
  const int b = blockIdx.x >> 4;
  const int tile = blockIdx.x & 15;
  const int w = threadIdx.x >> 6;
  const int lane = threadIdx.x & 63;

  if (blockIdx.x == 0 && threadIdx.x < 64) {   // fused prep (one wave)
    const int base = lane * 32;
    float e[32];
    float run = 0.f;
#pragma unroll
    for (int i = 0; i < 32; ++i) { e[i] = expf(v_emb[base + i]); run += e[i]; }
    float incl = run;
#pragma unroll
    for (int d = 1; d < 64; d <<= 1) {
      float up = __shfl_up(incl, d);
      if (lane >= d) incl += up;
    }
    float acc = incl - run;
#pragma unroll
    for (int i = 0; i < 32; ++i) {
      acc += e[i];
      Ebf[base + i] = f2bf(e[i]);
      S[base + i] = acc;
    }
  }

  const int k8base = tile * 16 + w * 4;        // this wave's 4 k8-groups
#pragma unroll
  for (int r = 0; r < 4; ++r) {
    const int k8 = k8base + r;
    unsigned short v[8];
#pragma unroll
    for (int j = 0; j < 8; ++j) {
      const int ii = idx[b * LSEQ + (2047 - (k8 * 8 + j))];  // wave-uniform
      v[j] = f2bf(Wq[ii * 64 + lane]);                       // coalesced row read
    }
    uint4 st;
    st.x = (unsigned int)v[0] | ((unsigned int)v[1] << 16);
    st.y = (unsigned int)v[2] | ((unsigned int)v[3] << 16);
    st.z = (unsigned int)v[4] | ((unsigned int)v[5] << 16);
    st.w = (unsigned int)v[6] | ((unsigned int)v[7] << 16);
    *(uint4*)(Agr + ((size_t)(b * 256 + k8) * 64 + lane) * 8) = st;  // 16B/lane coalesced
  }
}

// ---------------- K1: MFMA GEMM -> P[(b*64+c)][s] = exp(F/S[s]) ----------------
// Block = (b, 16-wide n-tile); 4 waves = 2 M-halves x 2 k-halves.
// Wave: M32 x N16, 2 MFMA per 32-k iter, ping-pong prefetch (LITERAL slots).
// GLv(i) = (127<=i<2175) ? E[i-127] : 0; staged window [96, n0+144).
__global__ __launch_bounds__(256, 8) void k_gemm(const unsigned short* __restrict__ Agr,
                                                 const unsigned short* __restrict__ Ebf,
                                                 const float* __restrict__ S,
                                                 float* __restrict__ P) {
  __shared__ unsigned short GL0[2208];   // GL0[i] = GLv(i)
  __shared__ unsigned short GL1[2176];   // GL1[i] = GLv(i+1)
  __shared__ float red[2][8][64];        // kh=1 partials per M-half

  const int b  = blockIdx.y;
  const int bn = 127 - (int)blockIdx.x;      // heavy (long-K) blocks first
  const int n0 = bn * 16;
  const int tid = threadIdx.x;
  const int w = tid >> 6;
  const int lane = tid & 63;
  const int quad = lane >> 4;
  const int lm = lane & 15;
  const int msub = w & 1;                    // M-half: c-offset 0 / 32
  const int kh = w >> 1;                     // k-half 0 / 1

  // stage the window this tile reads: i in [96, n0+144)
  {
    const int wend = n0 + 144;
    for (int i = 96 + tid; i < wend; i += 256) {
      const int e0 = i - 127;
      const int e1 = i - 126;
      GL0[i] = (e0 >= 0 && e0 < LSEQ) ? Ebf[e0] : (unsigned short)0;
      GL1[i] = (e1 >= 0 && e1 < LSEQ) ? Ebf[e1] : (unsigned short)0;
    }
  }
  __syncthreads();

  f32x4 acc0 = (f32x4){0.f, 0.f, 0.f, 0.f};
  f32x4 acc1 = (f32x4){0.f, 0.f, 0.f, 0.f};

  const int sbase = n0 + lm - 1920;
  const int kext = (n0 + 16 + 31) & ~31;     // K-extent rounded up to x32
  const int kstart = 2048 - kext;            // extra low-k entries hit GLv()=0
  const int iters = kext >> 5;               // total 32-k steps
  const unsigned short* __restrict__ abase = Agr + (size_t)b * 256 * 64 * 8;
  // parity of s_ is invariant across iters (k-step 64, quad*8 even)
  const unsigned int* __restrict__ gb =
      (sbase & 1) ? (const unsigned int*)GL1 : (const unsigned int*)GL0;

  union AF { uint4 u; bf16x8 v; };
  union BF { unsigned int u[4]; bf16x8 v; };
  AF a0_0, a0_1, a1_0, a1_1;                 // two slots x two m-tiles (LITERAL)
  BF b0, b1;

#define LOAD_FRAGS(J_, A0_, A1_, B_) do {                                   \
    const int k_ = kstart + (kh + 2 * (J_)) * 32;                           \
    const int kq8_ = (k_ >> 3) + quad;                                      \
    const unsigned short* ab_ = abase + ((size_t)kq8_ * 64 + msub * 32 + lm) * 8; \
    A0_.u = *(const uint4*)(ab_ + 0 * 128);                                 \
    A1_.u = *(const uint4*)(ab_ + 1 * 128);                                 \
    const int off_ = (sbase + k_ + quad * 8) >> 1;                          \
    B_.u[0] = gb[off_ + 0]; B_.u[1] = gb[off_ + 1];                         \
    B_.u[2] = gb[off_ + 2]; B_.u[3] = gb[off_ + 3];                         \
  } while (0)

#define MFMA2(A0_, A1_, B_) do {                                            \
    acc0 = __builtin_amdgcn_mfma_f32_16x16x32_bf16(A0_.v, B_.v, acc0, 0, 0, 0); \
    acc1 = __builtin_amdgcn_mfma_f32_16x16x32_bf16(A1_.v, B_.v, acc1, 0, 0, 0); \
  } while (0)

  const int J = (iters > kh) ? ((iters - kh + 1) >> 1) : 0;  // wave-iters
  if (J > 0) {
    LOAD_FRAGS(0, a0_0, a0_1, b0);
    int j = 0;
    while (true) {
      if (j + 1 < J) LOAD_FRAGS(j + 1, a1_0, a1_1, b1);
      MFMA2(a0_0, a0_1, b0);
      if (++j >= J) break;
      if (j + 1 < J) LOAD_FRAGS(j + 1, a0_0, a0_1, b0);
      MFMA2(a1_0, a1_1, b1);
      if (++j >= J) break;
    }
  }
#undef LOAD_FRAGS
#undef MFMA2

  // reduce k-half 1 into k-half 0 via LDS (lane-contiguous rows: conflict-free)
  if (kh == 1) {
#pragma unroll
    for (int r = 0; r < 4; ++r) {
      red[msub][r][lane] = acc0[r];
      red[msub][4 + r][lane] = acc1[r];
    }
  }
  __syncthreads();
  if (kh == 0) {
#pragma unroll
    for (int r = 0; r < 4; ++r) {
      acc0[r] += red[msub][r][lane];
      acc1[r] += red[msub][4 + r][lane];
    }

    // epilogue: C/D layout col(s)=lm, row(c)=quad*4+r
    const float sinv = 1.0f / S[n0 + lm];
#pragma unroll
    for (int r = 0; r < 4; ++r) {
      const int c0 = msub * 32 + quad * 4 + r;
      P[((size_t)(b * 64 + c0)) * LSEQ + n0 + lm] = __expf(acc0[r] * sinv);
      const int c1 = msub * 32 + 16 + quad * 4 + r;
      P[((size_t)(b * 64 + c1)) * LSEQ + n0 + lm] = __expf(acc1[r] * sinv);
    }
  }
}

// ---------------- K2: fused chunk-hists + scan + emission ----------------------
// Block per (b,c); wave w owns chunks w*8..w*8+7 (held in registers).
__global__ __launch_bounds__(256) void k_scanemit(const int* __restrict__ idx,
                                                  const float* __restrict__ P,
                                                  const float* __restrict__ Wv,
                                                  float* __restrict__ out) {
  __shared__ float Hs[NC][65];
  __shared__ float bins[4][64];
  const int bc = blockIdx.x;      // b*64 + c
  const int b = bc >> 6;
  const int c = bc & 63;
  const int w = threadIdx.x >> 6;
  const int lane = threadIdx.x & 63;

  const float* __restrict__ prow = P + (size_t)bc * LSEQ;
  const int* __restrict__ irow = idx + b * LSEQ;

  float p[8]; int ii[8];
#pragma unroll
  for (int r = 0; r < 8; ++r) {               // 16 independent coalesced loads
    const int ch = w * 8 + r;
    p[r] = prow[ch * 64 + lane];
    ii[r] = irow[ch * 64 + lane];
  }
  for (int i = threadIdx.x; i < NC * 65; i += 256) ((float*)Hs)[i] = 0.f;
  __syncthreads();
#pragma unroll
  for (int r = 0; r < 8; ++r) atomicAdd(&Hs[w * 8 + r][ii[r]], p[r]);
  __syncthreads();

  // exclusive scan across chunks, per bin: 2 bins per pass (lane halves)
  const int half = lane >> 5, l32 = lane & 31;
#pragma unroll
  for (int r = 0; r < 8; ++r) {
    const int v = w * 16 + r * 2 + half;
    const float h = Hs[l32][v];
    float x = h;
#pragma unroll
    for (int d = 1; d < 32; d <<= 1) {
      float up = __shfl_up(x, d, 32);
      if (l32 >= d) x += up;
    }
    Hs[l32][v] = x - h;                       // exclusive
  }
  __syncthreads();

  const float wv = Wv[0];
#pragma unroll
  for (int r = 0; r < 8; ++r) {
    const int ch = w * 8 + r;
    unsigned long long m = __ballot(ii[r] == c);   // emission points in chunk
    while (m) {
      const int srel = __builtin_ctzll(m);
      m &= m - 1;
      const int t = ch * 64 + srel;
      const float pm = (lane <= srel) ? p[r] : 0.f;  // causal mask
      bins[w][lane] = 0.f;
      __threadfence_block();
      atomicAdd(&bins[w][ii[r]], pm);              // one ds_add per emission
      __threadfence_block();
      const float bin = bins[w][lane] + Hs[ch][lane];
      float z = bin;
#pragma unroll
      for (int d = 1; d < 64; d <<= 1) z += __shfl_xor(z, d);
      out[((size_t)(b * LSEQ + t)) * 64 + lane] = wv * bin / z;
    }
  }
}

extern "C" void kernel_launch(void* const* d_in, const int* in_sizes, int n_in,
                              void* d_out, int out_size, void* d_ws, size_t ws_size,
                              hipStream_t stream) {
  const int* idx     = (const int*)d_in[0];     // [16, 2048]
  const float* Wq    = (const float*)d_in[1];   // [64, 64]
  const float* Wv    = (const float*)d_in[2];   // [64, 64] (only [0,0] used)
  const float* v_emb = (const float*)d_in[3];   // [2048, 1]
  float* out = (float*)d_out;                   // [16, 2048, 64] fp32

  // workspace: S[2048] f32 | P[1024*2048] f32 | Ebf[2048] bf16 | Agr[16*256*64*8] bf16
  float* S = (float*)d_ws;
  float* P = S + LSEQ;
  unsigned short* Ebf = (unsigned short*)(P + (size_t)NB * NV * LSEQ);
  unsigned short* Agr = Ebf + LSEQ;

  k_gather<<<NB * 16, 256, 0, stream>>>(idx, Wq, v_emb, Agr, Ebf, S);
  k_gemm<<<dim3(128, NB), 256, 0, stream>>>(Agr, Ebf, S, P);
  k_scanemit<<<NB * NV, 256, 0, stream>>>(idx, P, Wv, out);
}

// Round 14
// 120.157 us; speedup vs baseline: 2.4802x; 1.0131x over previous
//
#include <hip/hip_runtime.h>

// B=16, L=2048, V=64.
// Algebraic reduction (e is one-hot):
//   E[d] = exp(v_emb[d]); S[t] = prefix_sum(E)[t]
//   F[b,c,s] = sum_{k<=s} E[s-k] * Wq[idx[b,k], c]            (causal Toeplitz GEMM)
//   P[b,c,s] = exp(F[b,c,s] / S[s])                           (softmax w/o max; scores tiny)
//   out[b,t,v] = Wv00 * (sum_{s<=t, idx[b,s]==v} P[b,c_t,s]) / (sum_{s<=t} P[b,c_t,s]),  c_t = idx[b,t]
//
// R14 = R11 exactly (best measured: 120.47us). R12/R13 occupancy experiments
// were neutral-to-worse; R12's runtime-indexed pipeline slots spilled to
// scratch (250MB traffic). Totals are pinned at ~120us by the harness's
// 268MB 0xAA ws-poison fill (~45us, the only >44us dispatch in every profile).

#define LSEQ 2048
#define NB 16
#define NV 64
#define NC 32             // 32 chunks of 64

typedef __attribute__((ext_vector_type(8))) short bf16x8;
typedef __attribute__((ext_vector_type(4))) float f32x4;

__device__ __forceinline__ unsigned short f2bf(float f) {   // RNE float->bf16
  unsigned int u = __float_as_uint(f);
  return (unsigned short)((u + 0x7FFFu + ((u >> 16) & 1u)) >> 16);
}

// ---------------- K0: gather + (fused) prep ------------------------------------
// Agr[((b*256 + k8)*64 + c)*8 + j] = bf16(Wq[idx[b, 2047-(k8*8+j)]][c])
__global__ __launch_bounds__(256) void k_gather(const int* __restrict__ idx,
                                                const float* __restrict__ Wq,
                                                const float* __restrict__ v_emb,
                                                unsigned short* __restrict__ Agr,
                                                unsigned short* __restrict__ Ebf,
                                                float* __restrict__ S) {
  const int b = blockIdx.x >> 4;
  const int tile = blockIdx.x & 15;
  const int w = threadIdx.x >> 6;
  const int lane = threadIdx.x & 63;

  if (blockIdx.x == 0 && threadIdx.x < 64) {   // fused prep (one wave)
    const int base = lane * 32;
    float e[32];
    float run = 0.f;
#pragma unroll
    for (int i = 0; i < 32; ++i) { e[i] = expf(v_emb[base + i]); run += e[i]; }
    float incl = run;
#pragma unroll
    for (int d = 1; d < 64; d <<= 1) {
      float up = __shfl_up(incl, d);
      if (lane >= d) incl += up;
    }
    float acc = incl - run;
#pragma unroll
    for (int i = 0; i < 32; ++i) {
      acc += e[i];
      Ebf[base + i] = f2bf(e[i]);
      S[base + i] = acc;
    }
  }

  const int k8base = tile * 16 + w * 4;        // this wave's 4 k8-groups
#pragma unroll
  for (int r = 0; r < 4; ++r) {
    const int k8 = k8base + r;
    unsigned short v[8];
#pragma unroll
    for (int j = 0; j < 8; ++j) {
      const int ii = idx[b * LSEQ + (2047 - (k8 * 8 + j))];  // wave-uniform
      v[j] = f2bf(Wq[ii * 64 + lane]);                       // coalesced row read
    }
    uint4 st;
    st.x = (unsigned int)v[0] | ((unsigned int)v[1] << 16);
    st.y = (unsigned int)v[2] | ((unsigned int)v[3] << 16);
    st.z = (unsigned int)v[4] | ((unsigned int)v[5] << 16);
    st.w = (unsigned int)v[6] | ((unsigned int)v[7] << 16);
    *(uint4*)(Agr + ((size_t)(b * 256 + k8) * 64 + lane) * 8) = st;  // 16B/lane coalesced
  }
}

// ---------------- K1: MFMA GEMM -> P[(b*64+c)][s] = exp(F/S[s]) ----------------
// Block = (b, 32-wide n-tile); 4 waves = 2 n-subtiles x 2 k-halves.
// 3-buffer rotating pipeline; windowed E-staging ([96, n0+160) only).
__global__ __launch_bounds__(256) void k_gemm(const unsigned short* __restrict__ Agr,
                                              const unsigned short* __restrict__ Ebf,
                                              const float* __restrict__ S,
                                              float* __restrict__ P) {
  __shared__ unsigned short GL0[2208];   // GL0[i] = GLv(i)
  __shared__ unsigned short GL1[2176];   // GL1[i] = GLv(i+1)
  __shared__ float red[16][64];
  __shared__ float red2[16][64];
  // GLv(i) = (127<=i<2175) ? E[i-127] : 0

  const int b  = blockIdx.y;
  const int bn = 63 - (int)blockIdx.x;       // heavy (long-K) blocks first
  const int n0 = bn * 32;
  const int tid = threadIdx.x;
  const int w = tid >> 6;
  const int lane = tid & 63;
  const int quad = lane >> 4;
  const int lm = lane & 15;
  const int nsub = w & 1;                    // n-offset 0 / 16
  const int kh = w >> 1;                     // k-half 0 / 1

  // stage ONLY the window this tile reads: i in [96, n0+160)
  {
    const int wend = n0 + 160;
    for (int i = 96 + tid; i < wend; i += 256) {
      const int e0 = i - 127;
      const int e1 = i - 126;
      GL0[i] = (e0 >= 0 && e0 < LSEQ) ? Ebf[e0] : (unsigned short)0;
      GL1[i] = (e1 >= 0 && e1 < LSEQ) ? Ebf[e1] : (unsigned short)0;
    }
  }
  __syncthreads();

  f32x4 acc[4];
#pragma unroll
  for (int mt = 0; mt < 4; ++mt) acc[mt] = (f32x4){0.f, 0.f, 0.f, 0.f};

  const int nbase = n0 + nsub * 16;
  const int sbase = nbase + lm - 1920;
  const int kstart = 2048 - (n0 + 32);       // multiple of 32
  const int iters = bn + 1;                  // total 32-k steps for this tile
  const unsigned short* __restrict__ abase = Agr + (size_t)b * 256 * 64 * 8;

  union AF { uint4 u; bf16x8 v; };
  union BF { unsigned int u[4]; bf16x8 v; };
  AF a[3][4];
  BF bb[3];

#define LOAD_FRAGS(J_, SL) do {                                             \
    const int k_ = kstart + (kh + 2 * (J_)) * 32;                           \
    const int kq8_ = (k_ >> 3) + quad;                                      \
    const unsigned short* ab_ = abase + ((size_t)kq8_ * 64 + lm) * 8;       \
    a[SL][0].u = *(const uint4*)(ab_ + 0 * 128);                            \
    a[SL][1].u = *(const uint4*)(ab_ + 1 * 128);                            \
    a[SL][2].u = *(const uint4*)(ab_ + 2 * 128);                            \
    a[SL][3].u = *(const uint4*)(ab_ + 3 * 128);                            \
    const int s_ = sbase + k_ + quad * 8;                                   \
    const unsigned int* gb_ = (s_ & 1) ? (const unsigned int*)GL1           \
                                       : (const unsigned int*)GL0;          \
    const int off_ = s_ >> 1;                                               \
    bb[SL].u[0] = gb_[off_ + 0]; bb[SL].u[1] = gb_[off_ + 1];               \
    bb[SL].u[2] = gb_[off_ + 2]; bb[SL].u[3] = gb_[off_ + 3];               \
  } while (0)

#define MFMA4(SL) do {                                                      \
    acc[0] = __builtin_amdgcn_mfma_f32_16x16x32_bf16(a[SL][0].v, bb[SL].v, acc[0], 0, 0, 0); \
    acc[1] = __builtin_amdgcn_mfma_f32_16x16x32_bf16(a[SL][1].v, bb[SL].v, acc[1], 0, 0, 0); \
    acc[2] = __builtin_amdgcn_mfma_f32_16x16x32_bf16(a[SL][2].v, bb[SL].v, acc[2], 0, 0, 0); \
    acc[3] = __builtin_amdgcn_mfma_f32_16x16x32_bf16(a[SL][3].v, bb[SL].v, acc[3], 0, 0, 0); \
  } while (0)

  const int J = (iters > kh) ? ((iters - kh + 1) >> 1) : 0;  // wave-iters
  if (J > 0) {
    LOAD_FRAGS(0, 0);
    if (J > 1) LOAD_FRAGS(1, 1);
    int j = 0;
    while (true) {
      if (j + 2 < J) LOAD_FRAGS(j + 2, 2);
      MFMA4(0);
      if (++j >= J) break;
      if (j + 2 < J) LOAD_FRAGS(j + 2, 0);
      MFMA4(1);
      if (++j >= J) break;
      if (j + 2 < J) LOAD_FRAGS(j + 2, 1);
      MFMA4(2);
      if (++j >= J) break;
    }
  }
#undef LOAD_FRAGS
#undef MFMA4

  // reduce k-half 1 into k-half 0 via LDS (lane-contiguous rows: conflict-free)
  if (kh == 1) {
    float (*rd)[64] = nsub ? red2 : red;
#pragma unroll
    for (int mt = 0; mt < 4; ++mt)
#pragma unroll
      for (int r = 0; r < 4; ++r) rd[mt * 4 + r][lane] = acc[mt][r];
  }
  __syncthreads();
  if (kh == 0) {
    float (*rd)[64] = nsub ? red2 : red;
#pragma unroll
    for (int mt = 0; mt < 4; ++mt)
#pragma unroll
      for (int r = 0; r < 4; ++r) acc[mt][r] += rd[mt * 4 + r][lane];

    // epilogue: C/D layout col(s)=lm, row(c)=quad*4+r
    const float sinv = 1.0f / S[nbase + lm];
#pragma unroll
    for (int mt = 0; mt < 4; ++mt) {
#pragma unroll
      for (int r = 0; r < 4; ++r) {
        const int c = mt * 16 + quad * 4 + r;
        P[((size_t)(b * 64 + c)) * LSEQ + nbase + lm] = __expf(acc[mt][r] * sinv);
      }
    }
  }
}

// ---------------- K2: fused chunk-hists + scan + emission ----------------------
// Block per (b,c); wave w owns chunks w*8..w*8+7 (held in registers).
// (1) scatter chunk hists into Hs (stride-65 rows), (2) shfl exclusive scan
// across chunks per bin, (3) ballot-enumerate emission points t (idx[b,t]==c),
// (4) per t: masked single ds_add scatter + prefix + z-reduce + 256B store.
__global__ __launch_bounds__(256) void k_scanemit(const int* __restrict__ idx,
                                                  const float* __restrict__ P,
                                                  const float* __restrict__ Wv,
                                                  float* __restrict__ out) {
  __shared__ float Hs[NC][65];
  __shared__ float bins[4][64];
  const int bc = blockIdx.x;      // b*64 + c
  const int b = bc >> 6;
  const int c = bc & 63;
  const int w = threadIdx.x >> 6;
  const int lane = threadIdx.x & 63;

  const float* __restrict__ prow = P + (size_t)bc * LSEQ;
  const int* __restrict__ irow = idx + b * LSEQ;

  float p[8]; int ii[8];
#pragma unroll
  for (int r = 0; r < 8; ++r) {               // 16 independent coalesced loads
    const int ch = w * 8 + r;
    p[r] = prow[ch * 64 + lane];
    ii[r] = irow[ch * 64 + lane];
  }
  for (int i = threadIdx.x; i < NC * 65; i += 256) ((float*)Hs)[i] = 0.f;
  __syncthreads();
#pragma unroll
  for (int r = 0; r < 8; ++r) atomicAdd(&Hs[w * 8 + r][ii[r]], p[r]);
  __syncthreads();

  // exclusive scan across chunks, per bin: 2 bins per pass (lane halves)
  const int half = lane >> 5, l32 = lane & 31;
#pragma unroll
  for (int r = 0; r < 8; ++r) {
    const int v = w * 16 + r * 2 + half;
    const float h = Hs[l32][v];
    float x = h;
#pragma unroll
    for (int d = 1; d < 32; d <<= 1) {
      float up = __shfl_up(x, d, 32);
      if (l32 >= d) x += up;
    }
    Hs[l32][v] = x - h;                       // exclusive
  }
  __syncthreads();

  const float wv = Wv[0];
#pragma unroll
  for (int r = 0; r < 8; ++r) {
    const int ch = w * 8 + r;
    unsigned long long m = __ballot(ii[r] == c);   // emission points in chunk
    while (m) {
      const int srel = __builtin_ctzll(m);
      m &= m - 1;
      const int t = ch * 64 + srel;
      const float pm = (lane <= srel) ? p[r] : 0.f;  // causal mask
      bins[w][lane] = 0.f;
      __threadfence_block();
      atomicAdd(&bins[w][ii[r]], pm);              // one ds_add per emission
      __threadfence_block();
      const float bin = bins[w][lane] + Hs[ch][lane];
      float z = bin;
#pragma unroll
      for (int d = 1; d < 64; d <<= 1) z += __shfl_xor(z, d);
      out[((size_t)(b * LSEQ + t)) * 64 + lane] = wv * bin / z;
    }
  }
}

extern "C" void kernel_launch(void* const* d_in, const int* in_sizes, int n_in,
                              void* d_out, int out_size, void* d_ws, size_t ws_size,
                              hipStream_t stream) {
  const int* idx     = (const int*)d_in[0];     // [16, 2048]
  const float* Wq    = (const float*)d_in[1];   // [64, 64]
  const float* Wv    = (const float*)d_in[2];   // [64, 64] (only [0,0] used)
  const float* v_emb = (const float*)d_in[3];   // [2048, 1]
  float* out = (float*)d_out;                   // [16, 2048, 64] fp32

  // workspace: S[2048] f32 | P[1024*2048] f32 | Ebf[2048] bf16 | Agr[16*256*64*8] bf16
  float* S = (float*)d_ws;
  float* P = S + LSEQ;
  unsigned short* Ebf = (unsigned short*)(P + (size_t)NB * NV * LSEQ);
  unsigned short* Agr = Ebf + LSEQ;

  k_gather<<<NB * 16, 256, 0, stream>>>(idx, Wq, v_emb, Agr, Ebf, S);
  k_gemm<<<dim3(64, NB), 256, 0, stream>>>(Agr, Ebf, S, P);
  k_scanemit<<<NB * NV, 256, 0, stream>>>(idx, P, Wv, out);
}